// Round 2
// baseline (689.962 us; speedup 1.0000x reference)
//
#include <hip/hip_runtime.h>
#include <hip/hip_bf16.h>

// Problem dims (fixed by reference setup_inputs)
#define BB   2
#define CF_  64
#define CC   3
#define HH   64
#define WW   2048
#define HWs  (HH * WW)      // 131072
#define KK   9

// out[b, cf*9+n, h, w] = feat[b,cf,h+di,w+dj] * relu(M[cf,:]·rel[:,n])
// M = w1 @ w0  ([64,16]@[16,3] -> [64,3]), rel[c,n] = coordN - center (masked)
// All tensors float32 per the reference dtypes.
__global__ __launch_bounds__(256) void fused_unfold_mlp_kernel(
    const float* __restrict__ feat,
    const float* __restrict__ coord,
    const float* __restrict__ w0,
    const float* __restrict__ w1,
    float* __restrict__ out)
{
    __shared__ float Msh[CF_ * CC];   // 768 B

    const int t = threadIdx.x;
    // Each block redundantly computes M = w1@w0 (tiny: 192 dots of length 16).
    if (t < CF_ * CC) {
        const int o = t / CC, c = t - o * CC;
        float acc = 0.f;
#pragma unroll
        for (int k = 0; k < 16; k++)
            acc = fmaf(w1[o * 16 + k], w0[k * CC + c], acc);
        Msh[t] = acc;
    }
    __syncthreads();

    // One thread per (b,h,w). Grid covers the range exactly.
    const int p = blockIdx.x * 256 + t;
    const int w = p & (WW - 1);
    const int h = (p >> 11) & (HH - 1);
    const int b = p >> 17;

    // ---- coord: center + 9 neighbors, build masked rel[27] ----
    const float* __restrict__ cb = coord + (size_t)b * CC * HWs;
    float center[CC];
#pragma unroll
    for (int c = 0; c < CC; c++)
        center[c] = cb[c * HWs + h * WW + w];

    float rel[CC * KK];
    float validf[KK];
    int   offF[KK];
#pragma unroll
    for (int n = 0; n < KK; n++) {
        const int di = n / 3 - 1, dj = n % 3 - 1;
        const int hh = h + di, ww = w + dj;
        const bool v = (hh >= 0) && (hh < HH) && (ww >= 0) && (ww < WW);
        // clamp OOB address to own pixel (always valid), zero via validf
        offF[n]   = (v ? hh : h) * WW + (v ? ww : w);
        validf[n] = v ? 1.0f : 0.0f;
#pragma unroll
        for (int c = 0; c < CC; c++) {
            const float cn = cb[c * HWs + offF[n]] * validf[n];
            const float r  = cn - center[c];
            rel[c * KK + n] = (center[c] == -1.0f) ? 0.0f : r;
        }
    }

    // ---- main loop over feature channels ----
    const float* __restrict__ fb = feat + (size_t)b * CF_ * HWs;
    float* __restrict__ ob = out + (size_t)b * (CF_ * KK) * HWs
                                 + h * WW + w;

    for (int cf = 0; cf < CF_; cf++) {
        const float m0 = Msh[cf * CC + 0];
        const float m1 = Msh[cf * CC + 1];
        const float m2 = Msh[cf * CC + 2];
        const float* __restrict__ fcf = fb + (size_t)cf * HWs;
#pragma unroll
        for (int n = 0; n < KK; n++) {
            const float f = fcf[offF[n]] * validf[n];
            float wgt = fmaf(m2, rel[2 * KK + n],
                        fmaf(m1, rel[1 * KK + n], m0 * rel[n]));
            wgt = fmaxf(wgt, 0.0f);
            ob[(size_t)(cf * KK + n) * HWs] = f * wgt;
        }
    }
}

extern "C" void kernel_launch(void* const* d_in, const int* in_sizes, int n_in,
                              void* d_out, int out_size, void* d_ws, size_t ws_size,
                              hipStream_t stream) {
    const float* feat  = (const float*)d_in[0];
    const float* coord = (const float*)d_in[1];
    const float* w0    = (const float*)d_in[2];
    const float* w1    = (const float*)d_in[3];
    float* out = (float*)d_out;

    const int total  = BB * HH * WW;          // 262144 pixels
    const int blocks = total / 256;           // 1024
    fused_unfold_mlp_kernel<<<blocks, 256, 0, stream>>>(feat, coord, w0, w1, out);
}